// Round 7
// baseline (577.829 us; speedup 1.0000x reference)
//
#include <hip/hip_runtime.h>
#include <math.h>

// Problem constants (match reference)
#define NV 8192
#define EV 49152
#define KK 15625

typedef __attribute__((ext_vector_type(8))) short bf16x8;
typedef __attribute__((ext_vector_type(4))) float f32x4;

__device__ __forceinline__ unsigned short bf16rne(float x) {
    unsigned u = __float_as_uint(x);
    unsigned r = u + 0x7FFFu + ((u >> 16) & 1u);
    return (unsigned short)(r >> 16);
}
__device__ __forceinline__ float bf16tof(unsigned short h) {
    return __uint_as_float(((unsigned)h) << 16);
}

__device__ __forceinline__ void edge_frac(const float* __restrict__ pseudo, int e,
                                          float f[3], int lo[3]) {
#pragma unroll
    for (int j = 0; j < 3; ++j) {
        float v = pseudo[e * 3 + j] * 24.0f;
        float fl = floorf(v);
        int l = (int)fl;
        l = l < 0 ? 0 : (l > 23 ? 23 : l);
        lo[j] = l;
        f[j] = v - (float)l;
    }
}

// Prep: transform x -> h0, zero k-counts and dst-counts.
__global__ void prep_kernel(const float* __restrict__ x, float* __restrict__ h0,
                            int* __restrict__ counts, int* __restrict__ dcounts) {
    int gt = blockIdx.x * blockDim.x + threadIdx.x;  // grid covers >= KK
    if (gt < NV) {
        const float LC = -0.22703196f, UC = 0.36853024f;
        const float LM = 1.2585511f, UM = 1.648841f;
        const float R = 10.0f;
        float t0 = (x[gt * 2 + 0] - LC) / (UC - LC) * (2.0f * R) - R;
        float t1 = (x[gt * 2 + 1] - LM) / (UM - LM) * (2.0f * R) - R;
        h0[gt * 2 + 0] = fminf(fmaxf(t0, -R), R);
        h0[gt * 2 + 1] = fminf(fmaxf(t1, -R), R);
    }
    if (gt < KK) counts[gt] = 0;
    if (gt < NV) dcounts[gt] = 0;
}

// Histogram over kernel-index bins AND over dst bins (8 pairs per edge).
__global__ void hist_kernel(const float* __restrict__ pseudo, const int* __restrict__ ei,
                            int* __restrict__ counts, int* __restrict__ dcounts) {
    int e = blockIdx.x * blockDim.x + threadIdx.x;
    if (e >= EV) return;
    float f[3]; int lo[3];
    edge_frac(pseudo, e, f, lo);
#pragma unroll
    for (int s = 0; s < 8; ++s) {
        int wi = (lo[0] + (s & 1)) + 25 * (lo[1] + ((s >> 1) & 1)) + 625 * (lo[2] + ((s >> 2) & 1));
        atomicAdd(&counts[wi], 1);
    }
    atomicAdd(&dcounts[ei[EV + e]], 8);
}

// single-block exclusive scan over nbins
__global__ void scan_any(const int* __restrict__ counts, int* __restrict__ offsets,
                         int* __restrict__ cursor, int nbins) {
    __shared__ int sums[256];
    int t = threadIdx.x;
    int CH = (nbins + 255) / 256;
    int base = t * CH;
    int s = 0;
    for (int i = 0; i < CH; ++i) {
        int idx = base + i;
        if (idx < nbins) s += counts[idx];
    }
    sums[t] = s;
    __syncthreads();
    for (int d = 1; d < 256; d <<= 1) {
        int v = (t >= d) ? sums[t - d] : 0;
        __syncthreads();
        sums[t] += v;
        __syncthreads();
    }
    int run = (t > 0) ? sums[t - 1] : 0;
    for (int i = 0; i < CH; ++i) {
        int idx = base + i;
        if (idx < nbins) {
            offsets[idx] = run;
            cursor[idx] = run;
            run += counts[idx];
        }
    }
    if (t == 255) offsets[nbins] = run;
}

// Scatter: k-sorted pair list {src, b} plus the pair's dst-sorted slot q.
__global__ void scatter_kernel(const float* __restrict__ pseudo, const int* __restrict__ ei,
                               int* __restrict__ cursor, int* __restrict__ dcursor,
                               int2* __restrict__ pair_sb, int* __restrict__ pair_slot) {
    int e = blockIdx.x * blockDim.x + threadIdx.x;
    if (e >= EV) return;
    float f[3]; int lo[3];
    edge_frac(pseudo, e, f, lo);
    int src = ei[e];
    int dst = ei[EV + e];
#pragma unroll
    for (int s = 0; s < 8; ++s) {
        float b = ((s & 1) ? f[0] : 1.0f - f[0]) *
                  (((s >> 1) & 1) ? f[1] : 1.0f - f[1]) *
                  (((s >> 2) & 1) ? f[2] : 1.0f - f[2]);
        int wi = (lo[0] + (s & 1)) + 25 * (lo[1] + ((s >> 1) & 1)) + 625 * (lo[2] + ((s >> 2) & 1));
        int pos = atomicAdd(&cursor[wi], 1);
        int q = atomicAdd(&dcursor[dst], 1);
        pair_sb[pos] = make_int2(src, __float_as_int(b));
        pair_slot[pos] = q;
    }
}

// MFMA conv, message-writing version: per bucket k (k-sorted pairs), compute
// rows (b .* X[src]) @ W[k] and STORE each row to its dst-sorted slot in msg.
// No atomics. Columns split across waves (NT n-tiles per bucket).
template <int FIN, int FOUT>
__global__ __launch_bounds__(256) void conv_v6(
    const float* __restrict__ h, const float* __restrict__ W,
    const int* __restrict__ offsets, const int2* __restrict__ pair_sb,
    const int* __restrict__ pair_slot, float* __restrict__ msg) {
    constexpr int KT = FIN / 32;   // k-tiles
    constexpr int NT = FOUT / 16;  // n-tiles (waves per bucket)
    constexpr int BPB = 4 / NT;    // buckets per block
    int w = threadIdx.x >> 6;
    int lane = threadIdx.x & 63;
    int nslice = w % NT;
    int k = blockIdx.x * BPB + w / NT;
    if (k >= KK) return;
    int start = offsets[k];
    int n = offsets[k + 1] - start;
    if (n <= 0) return;
    int l15 = lane & 15;
    int lg = lane >> 4;  // 0..3

    // ---- B fragment: 16-column slice of W[k], hi+lo bf16 split ----
    const float* Wk = W + (size_t)k * (FIN * FOUT) + nslice * 16 + l15;
    bf16x8 Bh[KT], Bl[KT];
#pragma unroll
    for (int k0 = 0; k0 < KT; ++k0)
#pragma unroll
        for (int i = 0; i < 8; ++i) {
            float wv = Wk[(size_t)(k0 * 32 + lg * 8 + i) * FOUT];
            unsigned short hi = bf16rne(wv);
            unsigned short lo = bf16rne(wv - bf16tof(hi));
            Bh[k0][i] = (short)hi;
            Bl[k0][i] = (short)lo;
        }

    const int2* psb = pair_sb + start;
    const int* pslot = pair_slot + start;

    for (int m0 = 0; m0 < n; m0 += 16) {
        int ra = m0 + l15;
        bool va = ra < n;
        int2 sb = psb[va ? ra : 0];
        float b = va ? __int_as_float(sb.y) : 0.0f;
        const float* xr = h + (size_t)sb.x * FIN + lg * 8;

        f32x4 acc = (f32x4){0.f, 0.f, 0.f, 0.f};
#pragma unroll
        for (int k0 = 0; k0 < KT; ++k0) {
            float4 v0 = *(const float4*)(xr + k0 * 32);
            float4 v1 = *(const float4*)(xr + k0 * 32 + 4);
            float xv[8] = {v0.x * b, v0.y * b, v0.z * b, v0.w * b,
                           v1.x * b, v1.y * b, v1.z * b, v1.w * b};
            bf16x8 Ah, Al;
#pragma unroll
            for (int i = 0; i < 8; ++i) {
                unsigned short hi = bf16rne(xv[i]);
                unsigned short lo = bf16rne(xv[i] - bf16tof(hi));
                Ah[i] = (short)hi;
                Al[i] = (short)lo;
            }
            acc = __builtin_amdgcn_mfma_f32_16x16x32_bf16(Ah, Bh[k0], acc, 0, 0, 0);
            acc = __builtin_amdgcn_mfma_f32_16x16x32_bf16(Ah, Bl[k0], acc, 0, 0, 0);
            acc = __builtin_amdgcn_mfma_f32_16x16x32_bf16(Al, Bh[k0], acc, 0, 0, 0);
        }

        // ---- store: D[(lg*4+j)][l15] -> msg[q][nslice*16+l15] ----
#pragma unroll
        for (int j = 0; j < 4; ++j) {
            int rm = m0 + lg * 4 + j;
            if (rm < n) {
                int q = pslot[rm];
                msg[(size_t)q * FOUT + nslice * 16 + l15] = acc[j];
            }
        }
    }
}

// Layer 1 (FIN=2, FOUT=32): direct loads, store msg rows.
__global__ __launch_bounds__(256) void conv_l1(
    const float* __restrict__ h, const float* __restrict__ W,
    const int* __restrict__ offsets, const int2* __restrict__ pair_sb,
    const int* __restrict__ pair_slot, float* __restrict__ msg) {
    int w = threadIdx.x >> 6;
    int lane = threadIdx.x & 63;
    int k = blockIdx.x * 4 + w;
    if (k >= KK) return;
    int start = offsets[k];
    int n = offsets[k + 1] - start;
    if (n <= 0) return;
    int o = lane & 31;
    int g = lane >> 5;
    const float* Wk = W + (size_t)k * 64;
    float w0 = Wk[o], w1 = Wk[32 + o];
    const float2* h2 = (const float2*)h;
    for (int r = g; r < n; r += 2) {
        int2 sb = pair_sb[start + r];
        float b = __int_as_float(sb.y);
        int q = pair_slot[start + r];
        float2 xv = h2[sb.x];
        msg[(size_t)q * 32 + o] = b * (xv.x * w0 + xv.y * w1);
    }
}

// Layer 5 (FIN=32, FOUT=1): half-wave per row, shuffle reduce, store scalar.
__global__ __launch_bounds__(256) void conv_f1(
    const float* __restrict__ h, const float* __restrict__ W,
    const int* __restrict__ offsets, const int2* __restrict__ pair_sb,
    const int* __restrict__ pair_slot, float* __restrict__ msg) {
    int w = threadIdx.x >> 6;
    int lane = threadIdx.x & 63;
    int k = blockIdx.x * 4 + w;
    if (k >= KK) return;
    int start = offsets[k];
    int n = offsets[k + 1] - start;
    if (n <= 0) return;
    int i = lane & 31;
    int g = lane >> 5;
    float wk = W[(size_t)k * 32 + i];
    for (int r = g; r < n; r += 2) {
        int2 sb = pair_sb[start + r];
        float b = __int_as_float(sb.y);
        int q = pair_slot[start + r];
        float val = h[(size_t)sb.x * 32 + i] * wk * b;
#pragma unroll
        for (int d = 16; d >= 1; d >>= 1) val += __shfl_xor(val, d, 32);
        if (i == 0) msg[q] = val;
    }
}

// Fused reduce + node: one WAVE per node. Sum the node's contiguous msg
// segment (coalesced FOUT*4-byte rows), add h@root + bias, ELU, write h_out.
template <int FIN, int FOUT>
__global__ __launch_bounds__(256) void reduce_node(
    const float* __restrict__ h, const float* __restrict__ msg,
    const int* __restrict__ doffsets, const float* __restrict__ root,
    const float* __restrict__ bias, float* __restrict__ hout) {
    constexpr int RG = 64 / FOUT;  // rows per wave-iteration (1 or 2)
    int w = threadIdx.x >> 6;
    int lane = threadIdx.x & 63;
    int n = blockIdx.x * 4 + w;
    if (n >= NV) return;
    int seg0 = doffsets[n];
    int cnt = doffsets[n + 1] - seg0;
    int o = lane % FOUT;
    int gg = lane / FOUT;
    float acc = 0.0f;
    for (int r = gg; r < cnt; r += RG)
        acc += msg[(size_t)(seg0 + r) * FOUT + o];
    if (RG == 2) acc += __shfl_xor(acc, 32);
    float rt = bias[o];
#pragma unroll
    for (int i = 0; i < FIN; ++i) rt += h[(size_t)n * FIN + i] * root[i * FOUT + o];
    float v = acc + rt;
    v = v > 0.0f ? v : expm1f(v);
    if (gg == 0) hout[(size_t)n * FOUT + o] = v;
}

// Final layer reduce (FOUT=1): wave per node, lanes sum msg scalars + root dot.
__global__ __launch_bounds__(256) void reduce_node5(
    const float* __restrict__ h, const float* __restrict__ msg,
    const int* __restrict__ doffsets, const float* __restrict__ root,
    const float* __restrict__ bias, float* __restrict__ out) {
    int w = threadIdx.x >> 6;
    int lane = threadIdx.x & 63;
    int n = blockIdx.x * 4 + w;
    if (n >= NV) return;
    int seg0 = doffsets[n];
    int cnt = doffsets[n + 1] - seg0;
    float val = 0.0f;
    for (int r = lane; r < cnt; r += 64) val += msg[seg0 + r];
    if (lane < 32) val += h[(size_t)n * 32 + lane] * root[lane];
#pragma unroll
    for (int d = 32; d >= 1; d >>= 1) val += __shfl_xor(val, d, 64);
    if (lane == 0) {
        float v = val + bias[0];
        out[n] = v > 0.0f ? v : expm1f(v);
    }
}

extern "C" void kernel_launch(void* const* d_in, const int* in_sizes, int n_in,
                              void* d_out, int out_size, void* d_ws, size_t ws_size,
                              hipStream_t stream) {
    const float* x      = (const float*)d_in[0];
    const int*   ei     = (const int*)d_in[1];
    const float* pseudo = (const float*)d_in[2];
    const float* W1 = (const float*)d_in[3];
    const float* r1 = (const float*)d_in[4];
    const float* b1 = (const float*)d_in[5];
    const float* W2 = (const float*)d_in[6];
    const float* r2 = (const float*)d_in[7];
    const float* b2 = (const float*)d_in[8];
    const float* W3 = (const float*)d_in[9];
    const float* r3 = (const float*)d_in[10];
    const float* b3 = (const float*)d_in[11];
    const float* W4 = (const float*)d_in[12];
    const float* r4 = (const float*)d_in[13];
    const float* b4 = (const float*)d_in[14];
    const float* W5 = (const float*)d_in[15];
    const float* r5 = (const float*)d_in[16];
    const float* b5 = (const float*)d_in[17];

    char* ws = (char*)d_ws;
    size_t off = 0;
    auto alloc = [&](size_t bytes) {
        void* p = ws + off;
        off += (bytes + 255) & ~(size_t)255;
        return p;
    };
    int*   counts    = (int*)alloc(KK * sizeof(int));
    int*   offsets   = (int*)alloc((KK + 1) * sizeof(int));
    int*   cursor    = (int*)alloc(KK * sizeof(int));
    int*   dcounts   = (int*)alloc(NV * sizeof(int));
    int*   doffsets  = (int*)alloc((NV + 1) * sizeof(int));
    int*   dcursor   = (int*)alloc(NV * sizeof(int));
    int2*  pair_sb   = (int2*)alloc((size_t)EV * 8 * sizeof(int2));
    int*   pair_slot = (int*)alloc((size_t)EV * 8 * sizeof(int));
    float* hA        = (float*)alloc((size_t)NV * 64 * sizeof(float));
    float* hB        = (float*)alloc((size_t)NV * 64 * sizeof(float));
    float* msg       = (float*)alloc((size_t)EV * 8 * 64 * sizeof(float));  // 100.7 MB

    prep_kernel<<<(KK + 255) / 256, 256, 0, stream>>>(x, hA, counts, dcounts);
    hist_kernel<<<(EV + 255) / 256, 256, 0, stream>>>(pseudo, ei, counts, dcounts);
    scan_any<<<1, 256, 0, stream>>>(counts, offsets, cursor, KK);
    scan_any<<<1, 256, 0, stream>>>(dcounts, doffsets, dcursor, NV);
    scatter_kernel<<<(EV + 255) / 256, 256, 0, stream>>>(pseudo, ei, cursor, dcursor,
                                                         pair_sb, pair_slot);

    const int RGRID = (NV + 3) / 4;  // reduce: wave per node

    // Layer 1: [N,2] -> [N,32]   (hA -> hB)
    conv_l1<<<(KK + 3) / 4, 256, 0, stream>>>(hA, W1, offsets, pair_sb, pair_slot, msg);
    reduce_node<2, 32><<<RGRID, 256, 0, stream>>>(hA, msg, doffsets, r1, b1, hB);

    // Layer 2: [N,32] -> [N,64]  (hB -> hA)
    conv_v6<32, 64><<<KK, 256, 0, stream>>>(hB, W2, offsets, pair_sb, pair_slot, msg);
    reduce_node<32, 64><<<RGRID, 256, 0, stream>>>(hB, msg, doffsets, r2, b2, hA);

    // Layer 3: [N,64] -> [N,64]  (hA -> hB)
    conv_v6<64, 64><<<KK, 256, 0, stream>>>(hA, W3, offsets, pair_sb, pair_slot, msg);
    reduce_node<64, 64><<<RGRID, 256, 0, stream>>>(hA, msg, doffsets, r3, b3, hB);

    // Layer 4: [N,64] -> [N,32]  (hB -> hA)
    conv_v6<64, 32><<<(KK + 1) / 2, 256, 0, stream>>>(hB, W4, offsets, pair_sb, pair_slot, msg);
    reduce_node<64, 32><<<RGRID, 256, 0, stream>>>(hB, msg, doffsets, r4, b4, hA);

    // Layer 5: [N,32] -> [N,1]   (hA -> d_out)
    conv_f1<<<(KK + 3) / 4, 256, 0, stream>>>(hA, W5, offsets, pair_sb, pair_slot, msg);
    reduce_node5<<<RGRID, 256, 0, stream>>>(hA, msg, doffsets, r5, b5, (float*)d_out);
}

// Round 8
// 551.507 us; speedup vs baseline: 1.0477x; 1.0477x over previous
//
#include <hip/hip_runtime.h>
#include <math.h>

// Problem constants (match reference)
#define NV 8192
#define EV 49152
#define KK 15625

typedef __attribute__((ext_vector_type(8))) short bf16x8;
typedef __attribute__((ext_vector_type(4))) float f32x4;

__device__ __forceinline__ void atomAddF(float* p, float v) {
    unsafeAtomicAdd(p, v);  // native global_atomic_add_f32
}

__device__ __forceinline__ unsigned short bf16rne(float x) {
    unsigned u = __float_as_uint(x);
    unsigned r = u + 0x7FFFu + ((u >> 16) & 1u);
    return (unsigned short)(r >> 16);
}
__device__ __forceinline__ float bf16tof(unsigned short h) {
    return __uint_as_float(((unsigned)h) << 16);
}

__device__ __forceinline__ void edge_frac(const float* __restrict__ pseudo, int e,
                                          float f[3], int lo[3]) {
#pragma unroll
    for (int j = 0; j < 3; ++j) {
        float v = pseudo[e * 3 + j] * 24.0f;
        float fl = floorf(v);
        int l = (int)fl;
        l = l < 0 ? 0 : (l > 23 ? 23 : l);
        lo[j] = l;
        f[j] = v - (float)l;
    }
}

// Prep kernel: transform x -> h0, zero counts, zero agg (NV*64).
__global__ void prep_kernel(const float* __restrict__ x, float* __restrict__ h0,
                            int* __restrict__ counts, float* __restrict__ agg) {
    int gt = blockIdx.x * blockDim.x + threadIdx.x;  // grid = NV*64 threads
    if (gt < NV) {
        const float LC = -0.22703196f, UC = 0.36853024f;
        const float LM = 1.2585511f, UM = 1.648841f;
        const float R = 10.0f;
        float t0 = (x[gt * 2 + 0] - LC) / (UC - LC) * (2.0f * R) - R;
        float t1 = (x[gt * 2 + 1] - LM) / (UM - LM) * (2.0f * R) - R;
        h0[gt * 2 + 0] = fminf(fmaxf(t0, -R), R);
        h0[gt * 2 + 1] = fminf(fmaxf(t1, -R), R);
    }
    if (gt < KK) counts[gt] = 0;
    if (gt < NV * 64) agg[gt] = 0.0f;
}

__global__ void hist_kernel(const float* __restrict__ pseudo, int* __restrict__ counts) {
    int e = blockIdx.x * blockDim.x + threadIdx.x;
    if (e >= EV) return;
    float f[3]; int lo[3];
    edge_frac(pseudo, e, f, lo);
#pragma unroll
    for (int s = 0; s < 8; ++s) {
        int wi = (lo[0] + (s & 1)) + 25 * (lo[1] + ((s >> 1) & 1)) + 625 * (lo[2] + ((s >> 2) & 1));
        atomicAdd(&counts[wi], 1);
    }
}

// single-block exclusive scan over KK bins
__global__ void scan_kernel(const int* __restrict__ counts, int* __restrict__ offsets,
                            int* __restrict__ cursor) {
    __shared__ int sums[256];
    const int CH = 62;  // 256*62 = 15872 >= 15625
    int t = threadIdx.x;
    int base = t * CH;
    int s = 0;
    for (int i = 0; i < CH; ++i) {
        int idx = base + i;
        if (idx < KK) s += counts[idx];
    }
    sums[t] = s;
    __syncthreads();
    for (int d = 1; d < 256; d <<= 1) {
        int v = (t >= d) ? sums[t - d] : 0;
        __syncthreads();
        sums[t] += v;
        __syncthreads();
    }
    int run = (t > 0) ? sums[t - 1] : 0;
    for (int i = 0; i < CH; ++i) {
        int idx = base + i;
        if (idx < KK) {
            offsets[idx] = run;
            cursor[idx] = run;
            run += counts[idx];
        }
    }
    if (t == 255) offsets[KK] = run;
}

// Store (src, b) and dst per sorted pair.
__global__ void scatter_kernel(const float* __restrict__ pseudo, const int* __restrict__ ei,
                               int* __restrict__ cursor,
                               int2* __restrict__ pair_sb, int* __restrict__ pair_dst) {
    int e = blockIdx.x * blockDim.x + threadIdx.x;
    if (e >= EV) return;
    float f[3]; int lo[3];
    edge_frac(pseudo, e, f, lo);
    int src = ei[e];
    int dst = ei[EV + e];
#pragma unroll
    for (int s = 0; s < 8; ++s) {
        float b = ((s & 1) ? f[0] : 1.0f - f[0]) *
                  (((s >> 1) & 1) ? f[1] : 1.0f - f[1]) *
                  (((s >> 2) & 1) ? f[2] : 1.0f - f[2]);
        int wi = (lo[0] + (s & 1)) + 25 * (lo[1] + ((s >> 1) & 1)) + 625 * (lo[2] + ((s >> 2) & 1));
        int pos = atomicAdd(&cursor[wi], 1);
        pair_sb[pos] = make_int2(src, __float_as_int(b));
        pair_dst[pos] = dst;
    }
}

// MFMA conv v7: PERSISTENT waves. Each wave grid-strides over jobs
// (bucket k, col-slice nslice). Concurrent waves cover the NT slices of the
// same bucket (adjacent jobs) -> adjacent W reads, L2-friendly; a wave's
// next-job W loads overlap the current job's m-loop (no barriers anywhere).
// hi+lo bf16 split (3 MFMAs per logical product) keeps f32-grade accuracy.
template <int FIN, int FOUT>
__global__ __launch_bounds__(256) void conv_v7(
    const float* __restrict__ h, const float* __restrict__ W,
    const int* __restrict__ offsets, const int2* __restrict__ pair_sb,
    const int* __restrict__ pair_dst, float* __restrict__ agg) {
    constexpr int KT = FIN / 32;   // k-tiles
    constexpr int NT = FOUT / 16;  // n-tiles (col slices per bucket)
    const int J = KK * NT;
    int w = threadIdx.x >> 6;
    int lane = threadIdx.x & 63;
    int l15 = lane & 15;
    int lg = lane >> 4;  // 0..3
    int nwaves = gridDim.x * 4;

    for (int job = blockIdx.x * 4 + w; job < J; job += nwaves) {
        int k = job / NT;        // NT is a power of two -> shift
        int nslice = job % NT;
        int start = offsets[k];
        int n = offsets[k + 1] - start;
        if (n <= 0) continue;

        // ---- B fragment: 16-column slice of W[k], hi+lo bf16 split ----
        const float* Wk = W + (size_t)k * (FIN * FOUT) + nslice * 16 + l15;
        bf16x8 Bh[KT], Bl[KT];
#pragma unroll
        for (int k0 = 0; k0 < KT; ++k0)
#pragma unroll
            for (int i = 0; i < 8; ++i) {
                float wv = Wk[(size_t)(k0 * 32 + lg * 8 + i) * FOUT];
                unsigned short hi = bf16rne(wv);
                unsigned short lo = bf16rne(wv - bf16tof(hi));
                Bh[k0][i] = (short)hi;
                Bl[k0][i] = (short)lo;
            }

        const int2* psb = pair_sb + start;
        const int* pdst = pair_dst + start;

        for (int m0 = 0; m0 < n; m0 += 16) {
            int ra = m0 + l15;
            bool va = ra < n;
            int2 sb = psb[va ? ra : 0];
            float b = va ? __int_as_float(sb.y) : 0.0f;
            const float* xr = h + (size_t)sb.x * FIN + lg * 8;

            f32x4 acc = (f32x4){0.f, 0.f, 0.f, 0.f};
#pragma unroll
            for (int k0 = 0; k0 < KT; ++k0) {
                float4 v0 = *(const float4*)(xr + k0 * 32);
                float4 v1 = *(const float4*)(xr + k0 * 32 + 4);
                float xv[8] = {v0.x * b, v0.y * b, v0.z * b, v0.w * b,
                               v1.x * b, v1.y * b, v1.z * b, v1.w * b};
                bf16x8 Ah, Al;
#pragma unroll
                for (int i = 0; i < 8; ++i) {
                    unsigned short hi = bf16rne(xv[i]);
                    unsigned short lo = bf16rne(xv[i] - bf16tof(hi));
                    Ah[i] = (short)hi;
                    Al[i] = (short)lo;
                }
                acc = __builtin_amdgcn_mfma_f32_16x16x32_bf16(Ah, Bh[k0], acc, 0, 0, 0);
                acc = __builtin_amdgcn_mfma_f32_16x16x32_bf16(Ah, Bl[k0], acc, 0, 0, 0);
                acc = __builtin_amdgcn_mfma_f32_16x16x32_bf16(Al, Bh[k0], acc, 0, 0, 0);
            }

            // ---- scatter: D[(lg*4+j)][l15] ----
#pragma unroll
            for (int j = 0; j < 4; ++j) {
                int rm = m0 + lg * 4 + j;
                if (rm < n) {
                    int d = pdst[rm];
                    atomAddF(&agg[(size_t)d * FOUT + nslice * 16 + l15], acc[j]);
                }
            }
        }
    }
}

// Layer 1 (FIN=2, FOUT=32): persistent waves, one bucket per job.
__global__ __launch_bounds__(256) void conv_l1(
    const float* __restrict__ h, const float* __restrict__ W,
    const int* __restrict__ offsets, const int2* __restrict__ pair_sb,
    const int* __restrict__ pair_dst, float* __restrict__ agg) {
    int w = threadIdx.x >> 6;
    int lane = threadIdx.x & 63;
    int o = lane & 31;
    int g = lane >> 5;
    int nwaves = gridDim.x * 4;
    const float2* h2 = (const float2*)h;
    for (int k = blockIdx.x * 4 + w; k < KK; k += nwaves) {
        int start = offsets[k];
        int n = offsets[k + 1] - start;
        if (n <= 0) continue;
        const float* Wk = W + (size_t)k * 64;
        float w0 = Wk[o], w1 = Wk[32 + o];
        for (int r = g; r < n; r += 2) {
            int2 sb = pair_sb[start + r];
            float b = __int_as_float(sb.y);
            int dst = pair_dst[start + r];
            float2 xv = h2[sb.x];
            atomAddF(&agg[(size_t)dst * 32 + o], b * (xv.x * w0 + xv.y * w1));
        }
    }
}

// Layer 5 (FIN=32, FOUT=1): persistent waves, half-wave per row, shuffle reduce.
__global__ __launch_bounds__(256) void conv_f1(
    const float* __restrict__ h, const float* __restrict__ W,
    const int* __restrict__ offsets, const int2* __restrict__ pair_sb,
    const int* __restrict__ pair_dst, float* __restrict__ agg) {
    int w = threadIdx.x >> 6;
    int lane = threadIdx.x & 63;
    int i = lane & 31;
    int g = lane >> 5;
    int nwaves = gridDim.x * 4;
    for (int k = blockIdx.x * 4 + w; k < KK; k += nwaves) {
        int start = offsets[k];
        int n = offsets[k + 1] - start;
        if (n <= 0) continue;
        float wk = W[(size_t)k * 32 + i];
        for (int r = g; r < n; r += 2) {
            int2 sb = pair_sb[start + r];
            float b = __int_as_float(sb.y);
            int dst = pair_dst[start + r];
            float val = h[(size_t)sb.x * 32 + i] * wk * b;
#pragma unroll
            for (int d = 16; d >= 1; d >>= 1) val += __shfl_xor(val, d, 32);
            if (i == 0) atomAddF(&agg[dst], val);
        }
    }
}

// Node kernel: out = elu(agg + h@root + bias); also zeros agg[idx] (all NV*64)
// so the next conv needs no memset. Grid covers NV*64 threads.
template <int FIN, int FOUT>
__global__ void node_kernel(const float* __restrict__ h, float* __restrict__ agg,
                            const float* __restrict__ root, const float* __restrict__ bias,
                            float* __restrict__ hout) {
    int idx = blockIdx.x * blockDim.x + threadIdx.x;
    if (idx >= NV * 64) return;
    if (idx < NV * FOUT) {
        int n = idx / FOUT, o = idx % FOUT;
        float acc = agg[idx] + bias[o];
#pragma unroll
        for (int i = 0; i < FIN; ++i) acc += h[n * FIN + i] * root[i * FOUT + o];
        hout[idx] = acc > 0.0f ? acc : expm1f(acc);
    }
    agg[idx] = 0.0f;
}

extern "C" void kernel_launch(void* const* d_in, const int* in_sizes, int n_in,
                              void* d_out, int out_size, void* d_ws, size_t ws_size,
                              hipStream_t stream) {
    const float* x      = (const float*)d_in[0];
    const int*   ei     = (const int*)d_in[1];
    const float* pseudo = (const float*)d_in[2];
    const float* W1 = (const float*)d_in[3];
    const float* r1 = (const float*)d_in[4];
    const float* b1 = (const float*)d_in[5];
    const float* W2 = (const float*)d_in[6];
    const float* r2 = (const float*)d_in[7];
    const float* b2 = (const float*)d_in[8];
    const float* W3 = (const float*)d_in[9];
    const float* r3 = (const float*)d_in[10];
    const float* b3 = (const float*)d_in[11];
    const float* W4 = (const float*)d_in[12];
    const float* r4 = (const float*)d_in[13];
    const float* b4 = (const float*)d_in[14];
    const float* W5 = (const float*)d_in[15];
    const float* r5 = (const float*)d_in[16];
    const float* b5 = (const float*)d_in[17];

    char* ws = (char*)d_ws;
    size_t off = 0;
    auto alloc = [&](size_t bytes) {
        void* p = ws + off;
        off += (bytes + 255) & ~(size_t)255;
        return p;
    };
    int*   counts   = (int*)alloc(KK * sizeof(int));
    int*   offsets  = (int*)alloc((KK + 1) * sizeof(int));
    int*   cursor   = (int*)alloc(KK * sizeof(int));
    int2*  pair_sb  = (int2*)alloc((size_t)EV * 8 * sizeof(int2));
    int*   pair_dst = (int*)alloc((size_t)EV * 8 * sizeof(int));
    float* hA       = (float*)alloc((size_t)NV * 64 * sizeof(float));
    float* hB       = (float*)alloc((size_t)NV * 64 * sizeof(float));
    float* agg      = (float*)alloc((size_t)NV * 64 * sizeof(float));

    const int NGRID = (NV * 64 + 255) / 256;  // 2048 blocks
    const int CGRID = 2048;                   // persistent conv grid

    prep_kernel<<<NGRID, 256, 0, stream>>>(x, hA, counts, agg);
    hist_kernel<<<(EV + 255) / 256, 256, 0, stream>>>(pseudo, counts);
    scan_kernel<<<1, 256, 0, stream>>>(counts, offsets, cursor);
    scatter_kernel<<<(EV + 255) / 256, 256, 0, stream>>>(pseudo, ei, cursor, pair_sb, pair_dst);

    // Layer 1: [N,2] -> [N,32]   (hA -> hB)
    conv_l1<<<CGRID, 256, 0, stream>>>(hA, W1, offsets, pair_sb, pair_dst, agg);
    node_kernel<2, 32><<<NGRID, 256, 0, stream>>>(hA, agg, r1, b1, hB);

    // Layer 2: [N,32] -> [N,64]  (hB -> hA)
    conv_v7<32, 64><<<CGRID, 256, 0, stream>>>(hB, W2, offsets, pair_sb, pair_dst, agg);
    node_kernel<32, 64><<<NGRID, 256, 0, stream>>>(hB, agg, r2, b2, hA);

    // Layer 3: [N,64] -> [N,64]  (hA -> hB)
    conv_v7<64, 64><<<CGRID, 256, 0, stream>>>(hA, W3, offsets, pair_sb, pair_dst, agg);
    node_kernel<64, 64><<<NGRID, 256, 0, stream>>>(hA, agg, r3, b3, hB);

    // Layer 4: [N,64] -> [N,32]  (hB -> hA)
    conv_v7<64, 32><<<CGRID, 256, 0, stream>>>(hB, W4, offsets, pair_sb, pair_dst, agg);
    node_kernel<64, 32><<<NGRID, 256, 0, stream>>>(hB, agg, r4, b4, hA);

    // Layer 5: [N,32] -> [N,1]   (hA -> d_out)
    conv_f1<<<CGRID, 256, 0, stream>>>(hA, W5, offsets, pair_sb, pair_dst, agg);
    node_kernel<32, 1><<<NGRID, 256, 0, stream>>>(hA, agg, r5, b5, (float*)d_out);
}

// Round 9
// 551.138 us; speedup vs baseline: 1.0484x; 1.0007x over previous
//
#include <hip/hip_runtime.h>
#include <math.h>

// Problem constants (match reference)
#define NV 8192
#define EV 49152
#define KK 15625

typedef __attribute__((ext_vector_type(8))) short bf16x8;
typedef __attribute__((ext_vector_type(4))) float f32x4;

__device__ __forceinline__ void atomAddF(float* p, float v) {
    unsafeAtomicAdd(p, v);  // native global_atomic_add_f32
}

__device__ __forceinline__ unsigned short bf16rne(float x) {
    unsigned u = __float_as_uint(x);
    unsigned r = u + 0x7FFFu + ((u >> 16) & 1u);
    return (unsigned short)(r >> 16);
}
__device__ __forceinline__ float bf16tof(unsigned short h) {
    return __uint_as_float(((unsigned)h) << 16);
}

__device__ __forceinline__ void edge_frac(const float* __restrict__ pseudo, int e,
                                          float f[3], int lo[3]) {
#pragma unroll
    for (int j = 0; j < 3; ++j) {
        float v = pseudo[e * 3 + j] * 24.0f;
        float fl = floorf(v);
        int l = (int)fl;
        l = l < 0 ? 0 : (l > 23 ? 23 : l);
        lo[j] = l;
        f[j] = v - (float)l;
    }
}

// Prep: transform x -> h0 (f32, layer-1 only needs 2 floats/node), zero counts+agg.
__global__ void prep_kernel(const float* __restrict__ x, float* __restrict__ h0,
                            int* __restrict__ counts, float* __restrict__ agg) {
    int gt = blockIdx.x * blockDim.x + threadIdx.x;  // grid = NV*64 threads
    if (gt < NV) {
        const float LC = -0.22703196f, UC = 0.36853024f;
        const float LM = 1.2585511f, UM = 1.648841f;
        const float R = 10.0f;
        float t0 = (x[gt * 2 + 0] - LC) / (UC - LC) * (2.0f * R) - R;
        float t1 = (x[gt * 2 + 1] - LM) / (UM - LM) * (2.0f * R) - R;
        h0[gt * 2 + 0] = fminf(fmaxf(t0, -R), R);
        h0[gt * 2 + 1] = fminf(fmaxf(t1, -R), R);
    }
    if (gt < KK) counts[gt] = 0;
    if (gt < NV * 64) agg[gt] = 0.0f;
}

__global__ void hist_kernel(const float* __restrict__ pseudo, int* __restrict__ counts) {
    int e = blockIdx.x * blockDim.x + threadIdx.x;
    if (e >= EV) return;
    float f[3]; int lo[3];
    edge_frac(pseudo, e, f, lo);
#pragma unroll
    for (int s = 0; s < 8; ++s) {
        int wi = (lo[0] + (s & 1)) + 25 * (lo[1] + ((s >> 1) & 1)) + 625 * (lo[2] + ((s >> 2) & 1));
        atomicAdd(&counts[wi], 1);
    }
}

// single-block exclusive scan over KK bins
__global__ void scan_kernel(const int* __restrict__ counts, int* __restrict__ offsets,
                            int* __restrict__ cursor) {
    __shared__ int sums[256];
    const int CH = 62;
    int t = threadIdx.x;
    int base = t * CH;
    int s = 0;
    for (int i = 0; i < CH; ++i) {
        int idx = base + i;
        if (idx < KK) s += counts[idx];
    }
    sums[t] = s;
    __syncthreads();
    for (int d = 1; d < 256; d <<= 1) {
        int v = (t >= d) ? sums[t - d] : 0;
        __syncthreads();
        sums[t] += v;
        __syncthreads();
    }
    int run = (t > 0) ? sums[t - 1] : 0;
    for (int i = 0; i < CH; ++i) {
        int idx = base + i;
        if (idx < KK) {
            offsets[idx] = run;
            cursor[idx] = run;
            run += counts[idx];
        }
    }
    if (t == 255) offsets[KK] = run;
}

// Scatter: pair_src (gather side) and pair_db = {dst, b} (scatter side).
__global__ void scatter_kernel(const float* __restrict__ pseudo, const int* __restrict__ ei,
                               int* __restrict__ cursor,
                               int* __restrict__ pair_src, int2* __restrict__ pair_db) {
    int e = blockIdx.x * blockDim.x + threadIdx.x;
    if (e >= EV) return;
    float f[3]; int lo[3];
    edge_frac(pseudo, e, f, lo);
    int src = ei[e];
    int dst = ei[EV + e];
#pragma unroll
    for (int s = 0; s < 8; ++s) {
        float b = ((s & 1) ? f[0] : 1.0f - f[0]) *
                  (((s >> 1) & 1) ? f[1] : 1.0f - f[1]) *
                  (((s >> 2) & 1) ? f[2] : 1.0f - f[2]);
        int wi = (lo[0] + (s & 1)) + 25 * (lo[1] + ((s >> 1) & 1)) + 625 * (lo[2] + ((s >> 2) & 1));
        int pos = atomicAdd(&cursor[wi], 1);
        pair_src[pos] = src;
        pair_db[pos] = make_int2(dst, __float_as_int(b));
    }
}

// MFMA conv v8: persistent waves over (bucket, col-slice) jobs.
// h is PRE-SPLIT into bf16 hi/lo planes -> A-frags are direct 16-B loads,
// ZERO conversion VALU in the inner loop. b applied post-MFMA (per-row
// scalar, matches reference msg = basis * (xj @ W)). W converted to hi/lo
// in-kernel (each element touched exactly once). 3 MFMAs per k-tile
// (AhBh + AhBl + AlBh) give ~f32 accuracy.
template <int FIN, int FOUT>
__global__ __launch_bounds__(256) void conv_v8(
    const unsigned short* __restrict__ hhi, const unsigned short* __restrict__ hlo,
    const float* __restrict__ W,
    const int* __restrict__ offsets, const int* __restrict__ pair_src,
    const int2* __restrict__ pair_db, float* __restrict__ agg) {
    constexpr int KT = FIN / 32;   // k-tiles
    constexpr int NT = FOUT / 16;  // col slices per bucket
    const int J = KK * NT;
    int w = threadIdx.x >> 6;
    int lane = threadIdx.x & 63;
    int l15 = lane & 15;
    int lg = lane >> 4;  // 0..3
    int nwaves = gridDim.x * 4;

    for (int job = blockIdx.x * 4 + w; job < J; job += nwaves) {
        int k = job / NT;
        int nslice = job - k * NT;
        int start = offsets[k];
        int n = offsets[k + 1] - start;
        if (n <= 0) continue;

        // ---- B fragment: 16-col slice of W[k], hi+lo bf16 split ----
        const float* Wk = W + (size_t)k * (FIN * FOUT) + nslice * 16 + l15;
        bf16x8 Bh[KT], Bl[KT];
#pragma unroll
        for (int k0 = 0; k0 < KT; ++k0)
#pragma unroll
            for (int i = 0; i < 8; ++i) {
                float wv = Wk[(size_t)(k0 * 32 + lg * 8 + i) * FOUT];
                unsigned short hi = bf16rne(wv);
                unsigned short lo = bf16rne(wv - bf16tof(hi));
                Bh[k0][i] = (short)hi;
                Bl[k0][i] = (short)lo;
            }

        const int* psrc = pair_src + start;
        const int2* pdb = pair_db + start;

        for (int m0 = 0; m0 < n; m0 += 16) {
            int ra = m0 + l15;
            int src = psrc[ra < n ? ra : 0];
            const unsigned short* rhi = hhi + (size_t)src * FIN + lg * 8;
            const unsigned short* rlo = hlo + (size_t)src * FIN + lg * 8;

            f32x4 acc = (f32x4){0.f, 0.f, 0.f, 0.f};
#pragma unroll
            for (int k0 = 0; k0 < KT; ++k0) {
                bf16x8 Ah = *(const bf16x8*)(rhi + k0 * 32);
                bf16x8 Al = *(const bf16x8*)(rlo + k0 * 32);
                acc = __builtin_amdgcn_mfma_f32_16x16x32_bf16(Ah, Bh[k0], acc, 0, 0, 0);
                acc = __builtin_amdgcn_mfma_f32_16x16x32_bf16(Ah, Bl[k0], acc, 0, 0, 0);
                acc = __builtin_amdgcn_mfma_f32_16x16x32_bf16(Al, Bh[k0], acc, 0, 0, 0);
            }

            // ---- scatter: D[(lg*4+j)][l15], scaled by per-row b ----
#pragma unroll
            for (int j = 0; j < 4; ++j) {
                int rm = m0 + lg * 4 + j;
                if (rm < n) {
                    int2 db = pdb[rm];
                    atomAddF(&agg[(size_t)db.x * FOUT + nslice * 16 + l15],
                             acc[j] * __int_as_float(db.y));
                }
            }
        }
    }
}

// Layer 1 (FIN=2, FOUT=32): f32 input, persistent waves.
__global__ __launch_bounds__(256) void conv_l1(
    const float* __restrict__ h, const float* __restrict__ W,
    const int* __restrict__ offsets, const int* __restrict__ pair_src,
    const int2* __restrict__ pair_db, float* __restrict__ agg) {
    int w = threadIdx.x >> 6;
    int lane = threadIdx.x & 63;
    int o = lane & 31;
    int g = lane >> 5;
    int nwaves = gridDim.x * 4;
    const float2* h2 = (const float2*)h;
    for (int k = blockIdx.x * 4 + w; k < KK; k += nwaves) {
        int start = offsets[k];
        int n = offsets[k + 1] - start;
        if (n <= 0) continue;
        const float* Wk = W + (size_t)k * 64;
        float w0 = Wk[o], w1 = Wk[32 + o];
        for (int r = g; r < n; r += 2) {
            int src = pair_src[start + r];
            int2 db = pair_db[start + r];
            float b = __int_as_float(db.y);
            float2 xv = h2[src];
            atomAddF(&agg[(size_t)db.x * 32 + o], b * (xv.x * w0 + xv.y * w1));
        }
    }
}

// Layer 5 (FIN=32, FOUT=1): planes input, half-wave per row, shuffle reduce.
__global__ __launch_bounds__(256) void conv_f1(
    const unsigned short* __restrict__ hhi, const unsigned short* __restrict__ hlo,
    const float* __restrict__ W,
    const int* __restrict__ offsets, const int* __restrict__ pair_src,
    const int2* __restrict__ pair_db, float* __restrict__ agg) {
    int w = threadIdx.x >> 6;
    int lane = threadIdx.x & 63;
    int i = lane & 31;
    int g = lane >> 5;
    int nwaves = gridDim.x * 4;
    for (int k = blockIdx.x * 4 + w; k < KK; k += nwaves) {
        int start = offsets[k];
        int n = offsets[k + 1] - start;
        if (n <= 0) continue;
        float wk = W[(size_t)k * 32 + i];
        for (int r = g; r < n; r += 2) {
            int src = pair_src[start + r];
            int2 db = pair_db[start + r];
            float b = __int_as_float(db.y);
            float hv = bf16tof(hhi[(size_t)src * 32 + i]) + bf16tof(hlo[(size_t)src * 32 + i]);
            float val = hv * wk * b;
#pragma unroll
            for (int d = 16; d >= 1; d >>= 1) val += __shfl_xor(val, d, 32);
            if (i == 0) atomAddF(&agg[db.x], val);
        }
    }
}

// Node 1: f32 h (FIN=2) -> planes out (FOUT=32). Zeros agg.
__global__ void node1_kernel(const float* __restrict__ h, float* __restrict__ agg,
                             const float* __restrict__ root, const float* __restrict__ bias,
                             unsigned short* __restrict__ ohi, unsigned short* __restrict__ olo) {
    int idx = blockIdx.x * blockDim.x + threadIdx.x;
    if (idx >= NV * 64) return;
    if (idx < NV * 32) {
        int n = idx >> 5, o = idx & 31;
        float acc = agg[idx] + bias[o] + h[n * 2] * root[o] + h[n * 2 + 1] * root[32 + o];
        float v = acc > 0.0f ? acc : expm1f(acc);
        unsigned short hi = bf16rne(v);
        ohi[idx] = hi;
        olo[idx] = bf16rne(v - bf16tof(hi));
    }
    agg[idx] = 0.0f;
}

// Generic node: planes in (FIN) -> planes out (FOUT). Zeros agg.
template <int FIN, int FOUT>
__global__ void node_p(const unsigned short* __restrict__ hhi,
                       const unsigned short* __restrict__ hlo, float* __restrict__ agg,
                       const float* __restrict__ root, const float* __restrict__ bias,
                       unsigned short* __restrict__ ohi, unsigned short* __restrict__ olo) {
    int idx = blockIdx.x * blockDim.x + threadIdx.x;
    if (idx >= NV * 64) return;
    if (idx < NV * FOUT) {
        int n = idx / FOUT, o = idx % FOUT;
        float acc = agg[idx] + bias[o];
#pragma unroll
        for (int i = 0; i < FIN; ++i) {
            float hv = bf16tof(hhi[(size_t)n * FIN + i]) + bf16tof(hlo[(size_t)n * FIN + i]);
            acc += hv * root[i * FOUT + o];
        }
        float v = acc > 0.0f ? acc : expm1f(acc);
        unsigned short hi = bf16rne(v);
        ohi[idx] = hi;
        olo[idx] = bf16rne(v - bf16tof(hi));
    }
    agg[idx] = 0.0f;
}

// Node 5: planes in (FIN=32), agg scalars -> f32 out. One thread per node.
__global__ void node5_kernel(const unsigned short* __restrict__ hhi,
                             const unsigned short* __restrict__ hlo,
                             const float* __restrict__ agg, const float* __restrict__ root,
                             const float* __restrict__ bias, float* __restrict__ out) {
    int n = blockIdx.x * blockDim.x + threadIdx.x;
    if (n >= NV) return;
    float acc = agg[n] + bias[0];
#pragma unroll
    for (int i = 0; i < 32; ++i) {
        float hv = bf16tof(hhi[(size_t)n * 32 + i]) + bf16tof(hlo[(size_t)n * 32 + i]);
        acc += hv * root[i];
    }
    out[n] = acc > 0.0f ? acc : expm1f(acc);
}

extern "C" void kernel_launch(void* const* d_in, const int* in_sizes, int n_in,
                              void* d_out, int out_size, void* d_ws, size_t ws_size,
                              hipStream_t stream) {
    const float* x      = (const float*)d_in[0];
    const int*   ei     = (const int*)d_in[1];
    const float* pseudo = (const float*)d_in[2];
    const float* W1 = (const float*)d_in[3];
    const float* r1 = (const float*)d_in[4];
    const float* b1 = (const float*)d_in[5];
    const float* W2 = (const float*)d_in[6];
    const float* r2 = (const float*)d_in[7];
    const float* b2 = (const float*)d_in[8];
    const float* W3 = (const float*)d_in[9];
    const float* r3 = (const float*)d_in[10];
    const float* b3 = (const float*)d_in[11];
    const float* W4 = (const float*)d_in[12];
    const float* r4 = (const float*)d_in[13];
    const float* b4 = (const float*)d_in[14];
    const float* W5 = (const float*)d_in[15];
    const float* r5 = (const float*)d_in[16];
    const float* b5 = (const float*)d_in[17];

    char* ws = (char*)d_ws;
    size_t off = 0;
    auto alloc = [&](size_t bytes) {
        void* p = ws + off;
        off += (bytes + 255) & ~(size_t)255;
        return p;
    };
    int*   counts   = (int*)alloc(KK * sizeof(int));
    int*   offsets  = (int*)alloc((KK + 1) * sizeof(int));
    int*   cursor   = (int*)alloc(KK * sizeof(int));
    int*   pair_src = (int*)alloc((size_t)EV * 8 * sizeof(int));
    int2*  pair_db  = (int2*)alloc((size_t)EV * 8 * sizeof(int2));
    float* h0       = (float*)alloc((size_t)NV * 2 * sizeof(float));
    unsigned short* pAhi = (unsigned short*)alloc((size_t)NV * 64 * sizeof(unsigned short));
    unsigned short* pAlo = (unsigned short*)alloc((size_t)NV * 64 * sizeof(unsigned short));
    unsigned short* pBhi = (unsigned short*)alloc((size_t)NV * 64 * sizeof(unsigned short));
    unsigned short* pBlo = (unsigned short*)alloc((size_t)NV * 64 * sizeof(unsigned short));
    float* agg      = (float*)alloc((size_t)NV * 64 * sizeof(float));

    const int NGRID = (NV * 64 + 255) / 256;  // 2048
    const int CGRID = 2048;                   // persistent conv grid

    prep_kernel<<<NGRID, 256, 0, stream>>>(x, h0, counts, agg);
    hist_kernel<<<(EV + 255) / 256, 256, 0, stream>>>(pseudo, counts);
    scan_kernel<<<1, 256, 0, stream>>>(counts, offsets, cursor);
    scatter_kernel<<<(EV + 255) / 256, 256, 0, stream>>>(pseudo, ei, cursor, pair_src, pair_db);

    // Layer 1: [N,2] -> [N,32]   (h0 f32 -> planes A)
    conv_l1<<<CGRID, 256, 0, stream>>>(h0, W1, offsets, pair_src, pair_db, agg);
    node1_kernel<<<NGRID, 256, 0, stream>>>(h0, agg, r1, b1, pAhi, pAlo);

    // Layer 2: [N,32] -> [N,64]  (planes A -> planes B)
    conv_v8<32, 64><<<CGRID, 256, 0, stream>>>(pAhi, pAlo, W2, offsets, pair_src, pair_db, agg);
    node_p<32, 64><<<NGRID, 256, 0, stream>>>(pAhi, pAlo, agg, r2, b2, pBhi, pBlo);

    // Layer 3: [N,64] -> [N,64]  (planes B -> planes A)
    conv_v8<64, 64><<<CGRID, 256, 0, stream>>>(pBhi, pBlo, W3, offsets, pair_src, pair_db, agg);
    node_p<64, 64><<<NGRID, 256, 0, stream>>>(pBhi, pBlo, agg, r3, b3, pAhi, pAlo);

    // Layer 4: [N,64] -> [N,32]  (planes A -> planes B)
    conv_v8<64, 32><<<CGRID, 256, 0, stream>>>(pAhi, pAlo, W4, offsets, pair_src, pair_db, agg);
    node_p<64, 32><<<NGRID, 256, 0, stream>>>(pAhi, pAlo, agg, r4, b4, pBhi, pBlo);

    // Layer 5: [N,32] -> [N,1]   (planes B -> d_out)
    conv_f1<<<CGRID, 256, 0, stream>>>(pBhi, pBlo, W5, offsets, pair_src, pair_db, agg);
    node5_kernel<<<(NV + 255) / 256, 256, 0, stream>>>(pBhi, pBlo, agg, r5, b5, (float*)d_out);
}